// Round 4
// baseline (91.302 us; speedup 1.0000x reference)
//
#include <hip/hip_runtime.h>

#define N_NODES 10000
#define N_EDGES 320000
#define N_PAIRS 8192
#define IN_CH   128
#define HIDDEN  256
#define WPR     320   // u32 words per adjacency bitset row (320*32 = 10240 >= 10000)
#define WPR4    (WPR / 4)
#define TILE_B  16    // pairs per block; 512 blocks
#define TPP     16    // threads per pair in phase 1
#define CN_CAP  16    // common-neighbor list capacity per pair (overflow -> atomic path)
#define ADJ_BLOCKS (N_EDGES / 256)   // 1250

// --------------------------------------------- adjacency build + W1 pack
// W1 is [HIDDEN][2*IN_CH] row-major. Pack so thread h loads float4 of 4
// consecutive k at W1P[k4*HIDDEN + h]  (coalesced across h).
__global__ __launch_bounds__(256) void prep_kernel(const int* __restrict__ ei,
                                                   unsigned int* __restrict__ adj,
                                                   const float* __restrict__ W1,
                                                   float4* __restrict__ W1P) {
    int bid = blockIdx.x;
    int tid = threadIdx.x;
    if (bid < ADJ_BLOCKS) {
        int e = bid * 256 + tid;
        int u = ei[e];
        int v = ei[N_EDGES + e];
        atomicOr(&adj[(size_t)u * WPR + (v >> 5)], 1u << (v & 31));
        atomicOr(&adj[(size_t)v * WPR + (u >> 5)], 1u << (u & 31));
    } else {
        int k4 = bid - ADJ_BLOCKS;   // 0..63
        const float* src = W1 + (size_t)tid * HIDDEN + k4 * 4;
        W1P[(size_t)k4 * HIDDEN + tid] = make_float4(src[0], src[1], src[2], src[3]);
    }
}

// ------------------------------------------------- fused pair-xs + MLP
__global__ __launch_bounds__(256) void fused_kernel(const float* __restrict__ x,
                                                    const int* __restrict__ tei,
                                                    const unsigned int* __restrict__ adj,
                                                    const float4* __restrict__ W1P,
                                                    const float* __restrict__ b1,
                                                    const float* __restrict__ W2,
                                                    const float* __restrict__ b2,
                                                    float* __restrict__ out) {
    __shared__ float s_xs[TILE_B][2 * IN_CH];   // 16 KB
    __shared__ int   s_ij[TILE_B][2];
    __shared__ int   s_cnt[TILE_B];
    __shared__ int   s_cnl[TILE_B][CN_CAP];

    const int tid = threadIdx.x;
    const int p0 = blockIdx.x * TILE_B;

    if (tid < TILE_B) {
        s_ij[tid][0] = tei[p0 + tid];
        s_ij[tid][1] = tei[N_PAIRS + p0 + tid];
        s_cnt[tid] = 0;
    }
    // zero the cn_emb half of xs (512 float4 total)
    {
        float4* z = (float4*)s_xs;
        // cn region of pair b is float4 slots [b*64+32, b*64+64)
        for (int t = tid; t < TILE_B * 32; t += 256)
            z[(t >> 5) * 64 + 32 + (t & 31)] = make_float4(0.f, 0.f, 0.f, 0.f);
    }
    __syncthreads();

    // ---- phase 1a: bitset intersection, collect CN node ids
    const int b = tid >> 4;          // pair within tile (16 threads per pair)
    const int s = tid & 15;
    const int i = s_ij[b][0];
    const int j = s_ij[b][1];
    const uint4* ri4 = (const uint4*)(adj + (size_t)i * WPR);
    const uint4* rj4 = (const uint4*)(adj + (size_t)j * WPR);
    for (int q = s; q < WPR4; q += TPP) {    // 5 iterations
        uint4 a = ri4[q];
        uint4 c = rj4[q];
        unsigned int m[4] = { a.x & c.x, a.y & c.y, a.z & c.z, a.w & c.w };
#pragma unroll
        for (int w = 0; w < 4; ++w) {
            unsigned int mm = m[w];
            while (mm) {
                int bit = __builtin_ctz(mm);
                mm &= mm - 1;
                int n = q * 128 + w * 32 + bit;
                int pos = atomicAdd(&s_cnt[b], 1);
                if (pos < CN_CAP) {
                    s_cnl[b][pos] = n;
                } else {   // overflow (astronomically rare): direct LDS atomics
                    const float* xn = x + (size_t)n * IN_CH;
                    for (int d = 0; d < IN_CH; ++d)
                        atomicAdd(&s_xs[b][IN_CH + d], xn[d]);
                }
            }
        }
    }

    // ---- phase 1b: xij (each of the 16 threads owns 8 channels = 2 float4)
    {
        const float4* xi4 = (const float4*)(x + (size_t)i * IN_CH);
        const float4* xj4 = (const float4*)(x + (size_t)j * IN_CH);
        float4* xd = (float4*)&s_xs[b][0];
#pragma unroll
        for (int f = 0; f < 2; ++f) {
            float4 va = xi4[s * 2 + f];
            float4 vb = xj4[s * 2 + f];
            xd[s * 2 + f] = make_float4(va.x * vb.x, va.y * vb.y, va.z * vb.z, va.w * vb.w);
        }
    }
    __syncthreads();

    // ---- phase 1c: accumulate common-neighbor features (owner-computes)
    {
        int cnt = s_cnt[b];
        if (cnt > CN_CAP) cnt = CN_CAP;
        float4* dst = (float4*)&s_xs[b][IN_CH];
        float4 d0 = dst[s * 2];
        float4 d1 = dst[s * 2 + 1];
        for (int c = 0; c < cnt; ++c) {
            const float4* xn4 = (const float4*)(x + (size_t)s_cnl[b][c] * IN_CH);
            float4 v0 = xn4[s * 2];
            float4 v1 = xn4[s * 2 + 1];
            d0 = make_float4(d0.x + v0.x, d0.y + v0.y, d0.z + v0.z, d0.w + v0.w);
            d1 = make_float4(d1.x + v1.x, d1.y + v1.y, d1.z + v1.z, d1.w + v1.w);
        }
        dst[s * 2] = d0;
        dst[s * 2 + 1] = d1;
    }
    __syncthreads();

    // ---- phase 2: MLP. wave w owns pairs [4w,4w+4); lane owns h = lane+64r.
    const int wave = tid >> 6;
    const int lane = tid & 63;

    float acc[4][4];   // [pair][r]
#pragma unroll
    for (int bb = 0; bb < 4; ++bb)
#pragma unroll
        for (int r = 0; r < 4; ++r) acc[bb][r] = 0.0f;

    const float4* xs4 = (const float4*)s_xs;   // [16][64] float4
#pragma unroll 2
    for (int k4 = 0; k4 < HIDDEN / 4; ++k4) {
        float4 w0 = W1P[k4 * HIDDEN + lane];
        float4 w1 = W1P[k4 * HIDDEN + lane + 64];
        float4 w2 = W1P[k4 * HIDDEN + lane + 128];
        float4 w3 = W1P[k4 * HIDDEN + lane + 192];
#pragma unroll
        for (int bb = 0; bb < 4; ++bb) {
            float4 xv = xs4[(wave * 4 + bb) * 64 + k4];   // wave-uniform broadcast
            acc[bb][0] = fmaf(xv.x, w0.x, acc[bb][0]);
            acc[bb][0] = fmaf(xv.y, w0.y, acc[bb][0]);
            acc[bb][0] = fmaf(xv.z, w0.z, acc[bb][0]);
            acc[bb][0] = fmaf(xv.w, w0.w, acc[bb][0]);
            acc[bb][1] = fmaf(xv.x, w1.x, acc[bb][1]);
            acc[bb][1] = fmaf(xv.y, w1.y, acc[bb][1]);
            acc[bb][1] = fmaf(xv.z, w1.z, acc[bb][1]);
            acc[bb][1] = fmaf(xv.w, w1.w, acc[bb][1]);
            acc[bb][2] = fmaf(xv.x, w2.x, acc[bb][2]);
            acc[bb][2] = fmaf(xv.y, w2.y, acc[bb][2]);
            acc[bb][2] = fmaf(xv.z, w2.z, acc[bb][2]);
            acc[bb][2] = fmaf(xv.w, w2.w, acc[bb][2]);
            acc[bb][3] = fmaf(xv.x, w3.x, acc[bb][3]);
            acc[bb][3] = fmaf(xv.y, w3.y, acc[bb][3]);
            acc[bb][3] = fmaf(xv.z, w3.z, acc[bb][3]);
            acc[bb][3] = fmaf(xv.w, w3.w, acc[bb][3]);
        }
    }

    // ---- epilogue: relu, layer 2, per-pair wave reduction (no LDS)
    float bias[4], w2v[4];
#pragma unroll
    for (int r = 0; r < 4; ++r) {
        bias[r] = b1[lane + 64 * r];
        w2v[r]  = W2[lane + 64 * r];
    }
    const float bout = b2[0];
#pragma unroll
    for (int bb = 0; bb < 4; ++bb) {
        float v = 0.0f;
#pragma unroll
        for (int r = 0; r < 4; ++r)
            v += w2v[r] * fmaxf(acc[bb][r] + bias[r], 0.0f);
#pragma unroll
        for (int off = 32; off > 0; off >>= 1)
            v += __shfl_down(v, off);
        if (lane == 0) out[p0 + wave * 4 + bb] = v + bout;
    }
}

// -------------------------------------------------------------------- launch
extern "C" void kernel_launch(void* const* d_in, const int* in_sizes, int n_in,
                              void* d_out, int out_size, void* d_ws, size_t ws_size,
                              hipStream_t stream) {
    const float* x   = (const float*)d_in[0];
    const int*   ei  = (const int*)d_in[1];
    const int*   tei = (const int*)d_in[2];
    const float* W1  = (const float*)d_in[3];
    const float* b1  = (const float*)d_in[4];
    const float* W2  = (const float*)d_in[5];
    const float* b2  = (const float*)d_in[6];
    float* out = (float*)d_out;

    unsigned char* ws = (unsigned char*)d_ws;
    const size_t adj_bytes = (size_t)N_NODES * WPR * sizeof(unsigned int);   // 12.8 MB
    unsigned int* adj = (unsigned int*)ws;
    float4* W1P = (float4*)(ws + adj_bytes);                                 // 256 KB

    hipMemsetAsync(adj, 0, adj_bytes, stream);
    prep_kernel<<<ADJ_BLOCKS + HIDDEN / 4, 256, 0, stream>>>(ei, adj, W1, W1P);
    fused_kernel<<<N_PAIRS / TILE_B, 256, 0, stream>>>(x, tei, adj, W1P, b1, W2, b2, out);
}

// Round 5
// 77.410 us; speedup vs baseline: 1.1795x; 1.1795x over previous
//
#include <hip/hip_runtime.h>

#define N_NODES 10000
#define N_EDGES 320000
#define N_PAIRS 8192
#define IN_CH   128
#define HIDDEN  256
#define K_DIM   256   // 2*IN_CH
#define WPR     320   // u32 words per adjacency bitset row (320*32 = 10240 >= 10000)
#define WPR4    (WPR / 4)
#define TILE_B  8     // pairs per block; grid 1024
#define CN_CAP  16
#define ADJ_BLOCKS  (N_EDGES / 256)      // 1250
#define PACK_BLOCKS 32                   // 8192 threads pack B-fragments

typedef __attribute__((ext_vector_type(8))) short  short8;   // 8 bf16 (4 VGPRs)
typedef __attribute__((ext_vector_type(4))) float  f32x4;    // MFMA accumulator

static __device__ inline short f2bf(float f) {
    union { float f; unsigned u; } c; c.f = f;
    unsigned r = (c.u + 0x7FFFu + ((c.u >> 16) & 1u)) >> 16;   // RNE
    return (short)r;
}

// --------------------------------------------- adjacency build + W1 B-frag pack
// B-fragment for (k-step ks, n-tile t): lane l, elem e holds
//   W1T[k = ks*32 + (l>>4)*8 + e][n = t*16 + (l&15)]  =  W1[n][k]
// stored bf16 at W1B[((ks*16 + t)*64 + l)*8 + e]  -> fused reads 16B/lane coalesced.
__global__ __launch_bounds__(256) void prep_kernel(const int* __restrict__ ei,
                                                   unsigned int* __restrict__ adj,
                                                   const float* __restrict__ W1,
                                                   short* __restrict__ W1B) {
    int bid = blockIdx.x;
    int tid = threadIdx.x;
    if (bid < ADJ_BLOCKS) {
        int e = bid * 256 + tid;
        int u = ei[e];
        int v = ei[N_EDGES + e];
        atomicOr(&adj[(size_t)u * WPR + (v >> 5)], 1u << (v & 31));
        atomicOr(&adj[(size_t)v * WPR + (u >> 5)], 1u << (u & 31));
    } else {
        int t2 = (bid - ADJ_BLOCKS) * 256 + tid;   // 0..8191
        int ks = t2 >> 10;                          // 0..7
        int t  = (t2 >> 6) & 15;                    // n-tile 0..15
        int l  = t2 & 63;                           // lane
        int n  = t * 16 + (l & 15);
        int kb = ks * 32 + ((l >> 4) << 3);
        const float* src = W1 + (size_t)n * K_DIM + kb;
        short* dst = W1B + ((size_t)(ks * 16 + t) * 64 + l) * 8;
#pragma unroll
        for (int e = 0; e < 8; ++e) dst[e] = f2bf(src[e]);
    }
}

// ------------------------------------------------- fused pair-xs + MFMA MLP
__global__ __launch_bounds__(256) void fused_kernel(const float* __restrict__ x,
                                                    const int* __restrict__ tei,
                                                    const unsigned int* __restrict__ adj,
                                                    const short* __restrict__ W1B,
                                                    const float* __restrict__ b1,
                                                    const float* __restrict__ W2,
                                                    const float* __restrict__ b2,
                                                    float* __restrict__ out) {
    // xs stored as float4 units, XOR-swizzled: unit f of row b lives at b*64 + (f ^ (b&7))
    __shared__ float4 s_xs4[TILE_B * 64];     // 8 KB
    __shared__ int    s_ij[TILE_B][2];
    __shared__ int    s_cnt[TILE_B];
    __shared__ int    s_cnl[TILE_B][CN_CAP];
    __shared__ float  s_part[TILE_B][4];

    const int tid = threadIdx.x;
    const int p0 = blockIdx.x * TILE_B;

    if (tid < TILE_B) {
        s_ij[tid][0] = tei[p0 + tid];
        s_ij[tid][1] = tei[N_PAIRS + p0 + tid];
        s_cnt[tid] = 0;
    }
    // zero cn_emb half (units 32..63 of each row): exactly one unit per thread
    {
        int b = tid >> 5, u = 32 + (tid & 31);
        s_xs4[b * 64 + (u ^ (b & 7))] = make_float4(0.f, 0.f, 0.f, 0.f);
    }
    __syncthreads();

    // ---- phase 1: intersection + xij (32 threads per pair; pairs wave-local)
    const int b = tid >> 5;
    const int s = tid & 31;
    const int i = s_ij[b][0];
    const int j = s_ij[b][1];

    const float4* xi4 = (const float4*)(x + (size_t)i * IN_CH);
    const float4* xj4 = (const float4*)(x + (size_t)j * IN_CH);
    float4 va = xi4[s];                      // issue early
    float4 vb = xj4[s];

    const uint4* ri4 = (const uint4*)(adj + (size_t)i * WPR);
    const uint4* rj4 = (const uint4*)(adj + (size_t)j * WPR);
    for (int q = s; q < WPR4; q += 32) {     // 2-3 iterations
        uint4 a = ri4[q];
        uint4 c = rj4[q];
        unsigned int m[4] = { a.x & c.x, a.y & c.y, a.z & c.z, a.w & c.w };
#pragma unroll
        for (int w = 0; w < 4; ++w) {
            unsigned int mm = m[w];
            while (mm) {
                int bit = __builtin_ctz(mm);
                mm &= mm - 1;
                int n = q * 128 + w * 32 + bit;
                int pos = atomicAdd(&s_cnt[b], 1);
                if (pos < CN_CAP) {
                    s_cnl[b][pos] = n;
                } else {   // astronomically rare overflow: swizzle-aware LDS atomics
                    const float* xn = x + (size_t)n * IN_CH;
                    for (int d = 0; d < IN_CH; ++d) {
                        int fidx = IN_CH + d;
                        int u = fidx >> 2;
                        float* base = (float*)&s_xs4[b * 64 + (u ^ (b & 7))];
                        atomicAdd(&base[fidx & 3], xn[d]);
                    }
                }
            }
        }
    }

    // xij: unit s of row b
    s_xs4[b * 64 + (s ^ (b & 7))] =
        make_float4(va.x * vb.x, va.y * vb.y, va.z * vb.z, va.w * vb.w);

    // cn_emb accumulate (owner-computes, unit 32+s)
    {
        int cnt = s_cnt[b];
        if (cnt > CN_CAP) cnt = CN_CAP;
        int u = (32 + s) ^ (b & 7);
        float4 d0 = s_xs4[b * 64 + u];
        for (int c = 0; c < cnt; ++c) {
            const float4* xn4 = (const float4*)(x + (size_t)s_cnl[b][c] * IN_CH);
            float4 v = xn4[s];
            d0 = make_float4(d0.x + v.x, d0.y + v.y, d0.z + v.z, d0.w + v.w);
        }
        s_xs4[b * 64 + u] = d0;
    }
    __syncthreads();

    // ---- phase 2: MFMA MLP. wave w covers h-cols [64w, 64w+64), all 8 pairs.
    const int w    = tid >> 6;
    const int lane = tid & 63;
    const int mr   = lane & 7;     // A row (lanes 8-15 duplicate rows 0-7; their C rows unused)
    const int kb   = lane >> 4;    // k-block 0..3

    f32x4 acc0 = {0.f, 0.f, 0.f, 0.f};
    f32x4 acc1 = {0.f, 0.f, 0.f, 0.f};
    f32x4 acc2 = {0.f, 0.f, 0.f, 0.f};
    f32x4 acc3 = {0.f, 0.f, 0.f, 0.f};

    const short8* W1B8 = (const short8*)W1B;
    for (int ks = 0; ks < 8; ++ks) {
        int f0 = ks * 8 + kb * 2;
        float4 x0 = s_xs4[mr * 64 + (f0 ^ mr)];
        float4 x1 = s_xs4[mr * 64 + ((f0 + 1) ^ mr)];
        short8 af;
        af[0] = f2bf(x0.x); af[1] = f2bf(x0.y); af[2] = f2bf(x0.z); af[3] = f2bf(x0.w);
        af[4] = f2bf(x1.x); af[5] = f2bf(x1.y); af[6] = f2bf(x1.z); af[7] = f2bf(x1.w);
        int fb = (ks * 16 + w * 4) * 64 + lane;
        short8 bf0 = W1B8[fb];
        short8 bf1 = W1B8[fb + 64];
        short8 bf2 = W1B8[fb + 128];
        short8 bf3 = W1B8[fb + 192];
        acc0 = __builtin_amdgcn_mfma_f32_16x16x32_bf16(af, bf0, acc0, 0, 0, 0);
        acc1 = __builtin_amdgcn_mfma_f32_16x16x32_bf16(af, bf1, acc1, 0, 0, 0);
        acc2 = __builtin_amdgcn_mfma_f32_16x16x32_bf16(af, bf2, acc2, 0, 0, 0);
        acc3 = __builtin_amdgcn_mfma_f32_16x16x32_bf16(af, bf3, acc3, 0, 0, 0);
    }

    // ---- epilogue: relu + layer 2 (fp32), reduce over h
    // C layout: col = lane&15 (n within tile), row = (lane>>4)*4 + reg (pair)
    const int ncol = lane & 15;
    float sum[4] = {0.f, 0.f, 0.f, 0.f};
#pragma unroll
    for (int t = 0; t < 4; ++t) {
        int n = w * 64 + t * 16 + ncol;
        float b1v = b1[n];
        float w2v = W2[n];
        const f32x4& a = (t == 0) ? acc0 : (t == 1) ? acc1 : (t == 2) ? acc2 : acc3;
#pragma unroll
        for (int r = 0; r < 4; ++r)
            sum[r] += w2v * fmaxf(a[r] + b1v, 0.f);
    }
#pragma unroll
    for (int r = 0; r < 4; ++r) {
        float v = sum[r];
        v += __shfl_xor(v, 1);
        v += __shfl_xor(v, 2);
        v += __shfl_xor(v, 4);
        v += __shfl_xor(v, 8);
        if ((lane & 15) == 0) {
            int mrow = (lane >> 4) * 4 + r;
            if (mrow < TILE_B) s_part[mrow][w] = v;
        }
    }
    __syncthreads();

    if (tid < TILE_B) {
        out[p0 + tid] = b2[0] + s_part[tid][0] + s_part[tid][1]
                               + s_part[tid][2] + s_part[tid][3];
    }
}

// -------------------------------------------------------------------- launch
extern "C" void kernel_launch(void* const* d_in, const int* in_sizes, int n_in,
                              void* d_out, int out_size, void* d_ws, size_t ws_size,
                              hipStream_t stream) {
    const float* x   = (const float*)d_in[0];
    const int*   ei  = (const int*)d_in[1];
    const int*   tei = (const int*)d_in[2];
    const float* W1  = (const float*)d_in[3];
    const float* b1  = (const float*)d_in[4];
    const float* W2  = (const float*)d_in[5];
    const float* b2  = (const float*)d_in[6];
    float* out = (float*)d_out;

    unsigned char* ws = (unsigned char*)d_ws;
    const size_t adj_bytes = (size_t)N_NODES * WPR * sizeof(unsigned int);   // 12.8 MB
    unsigned int* adj = (unsigned int*)ws;
    short* W1B = (short*)(ws + adj_bytes);                                   // 128 KB bf16

    hipMemsetAsync(adj, 0, adj_bytes, stream);
    prep_kernel<<<ADJ_BLOCKS + PACK_BLOCKS, 256, 0, stream>>>(ei, adj, W1, W1B);
    fused_kernel<<<N_PAIRS / TILE_B, 256, 0, stream>>>(x, tei, adj, W1B, b1, W2, b2, out);
}

// Round 9
// 55.943 us; speedup vs baseline: 1.6321x; 1.3837x over previous
//
#include <hip/hip_runtime.h>

#define N_NODES 10000
#define N_EDGES 320000
#define N_PAIRS 8192
#define IN_CH   128
#define HIDDEN  256
#define K_DIM   256   // 2*IN_CH
#define WPR     320   // u32 words per adjacency bitset row (320*32 = 10240 >= 10000)
#define WPR4    (WPR / 4)
#define TILE_B  16    // pairs per block; grid 512, 512 threads/block
#define CN_CAP  64    // list capacity; i==j pairs (deg~64) overflow -> LDS atomic path
#define ZERO_BLOCKS (N_NODES * WPR / 4 / 256)   // 3125 (uint4 units)
#define PACK_BLOCKS 32
#define ADJ_BLOCKS  (N_EDGES / 256)             // 1250

typedef __attribute__((ext_vector_type(8))) short  short8;   // 8 bf16 (4 VGPRs)
typedef __attribute__((ext_vector_type(4))) float  f32x4;    // MFMA accumulator

static __device__ inline short f2bf(float f) {
    union { float f; unsigned u; } c; c.f = f;
    unsigned r = (c.u + 0x7FFFu + ((c.u >> 16) & 1u)) >> 16;   // RNE
    return (short)r;
}

// ---------------------------------------------- zero adjacency + pack W1
// B-fragment for (k-step ks, n-tile t): lane l, elem e holds
//   W1[n = t*16 + (l&15)][k = ks*32 + (l>>4)*8 + e]   (bf16)
// at W1B[((ks*16 + t)*64 + l)*8 + e].
__global__ __launch_bounds__(256) void zero_pack_kernel(uint4* __restrict__ adj4,
                                                        const float* __restrict__ W1,
                                                        short* __restrict__ W1B) {
    int bid = blockIdx.x;
    int tid = threadIdx.x;
    if (bid < ZERO_BLOCKS) {
        adj4[(size_t)bid * 256 + tid] = make_uint4(0u, 0u, 0u, 0u);
    } else {
        int t2 = (bid - ZERO_BLOCKS) * 256 + tid;   // 0..8191
        int ks = t2 >> 10;                          // 0..7
        int t  = (t2 >> 6) & 15;                    // n-tile 0..15
        int l  = t2 & 63;                           // lane
        int n  = t * 16 + (l & 15);
        int kb = ks * 32 + ((l >> 4) << 3);
        const float* src = W1 + (size_t)n * K_DIM + kb;
        short* dst = W1B + ((size_t)(ks * 16 + t) * 64 + l) * 8;
#pragma unroll
        for (int e = 0; e < 8; ++e) dst[e] = f2bf(src[e]);
    }
}

// ---------------------------------------------------------------- adjacency
__global__ __launch_bounds__(256) void build_adj_kernel(const int* __restrict__ ei,
                                                        unsigned int* __restrict__ adj) {
    int e = blockIdx.x * blockDim.x + threadIdx.x;   // grid*block == N_EDGES exactly
    int u = ei[e];
    int v = ei[N_EDGES + e];
    atomicOr(&adj[(size_t)u * WPR + (v >> 5)], 1u << (v & 31));
    atomicOr(&adj[(size_t)v * WPR + (u >> 5)], 1u << (u & 31));
}

// ------------------------------------------------- fused pair-xs + MFMA MLP
__global__ __launch_bounds__(512) void fused_kernel(const float* __restrict__ x,
                                                    const int* __restrict__ tei,
                                                    const unsigned int* __restrict__ adj,
                                                    const short* __restrict__ W1B,
                                                    const float* __restrict__ b1,
                                                    const float* __restrict__ W2,
                                                    const float* __restrict__ b2,
                                                    float* __restrict__ out) {
    // xs as float4 units: unit u of row b at b*64 + (u ^ (b&7))
    __shared__ float4 s_xs4[TILE_B * 64];     // 16 KB
    __shared__ int    s_ij[TILE_B][2];
    __shared__ int    s_cnt[TILE_B];
    __shared__ int    s_cnl[TILE_B][CN_CAP];  // 4 KB
    __shared__ float  s_part[TILE_B][8];

    const int tid = threadIdx.x;
    const int p0 = blockIdx.x * TILE_B;

    if (tid < TILE_B) {
        s_ij[tid][0] = tei[p0 + tid];
        s_ij[tid][1] = tei[N_PAIRS + p0 + tid];
        s_cnt[tid] = 0;
    }
    // zero CN half (units 32..63 of each row; XOR-swizzle is a bijection on it,
    // so zero linearly). 512 threads = 16 rows x 32 units, own-pair's row.
    {
        int zb = tid >> 5, zu = 32 + (tid & 31);
        s_xs4[zb * 64 + zu] = make_float4(0.f, 0.f, 0.f, 0.f);
    }
    __syncthreads();

    // ---- phase 1: intersection + xij (32 threads per pair; pair within one wave)
    const int b = tid >> 5;
    const int s = tid & 31;
    const int i = s_ij[b][0];
    const int j = s_ij[b][1];

    const float4* xi4 = (const float4*)(x + (size_t)i * IN_CH);
    const float4* xj4 = (const float4*)(x + (size_t)j * IN_CH);
    float4 va = xi4[s];                      // issue early
    float4 vb = xj4[s];

    const uint4* ri4 = (const uint4*)(adj + (size_t)i * WPR);
    const uint4* rj4 = (const uint4*)(adj + (size_t)j * WPR);
    for (int q = s; q < WPR4; q += 32) {     // 2-3 iterations
        uint4 a = ri4[q];
        uint4 c = rj4[q];
        unsigned int m[4] = { a.x & c.x, a.y & c.y, a.z & c.z, a.w & c.w };
#pragma unroll
        for (int ww = 0; ww < 4; ++ww) {
            unsigned int mm = m[ww];
            while (mm) {
                int bit = __builtin_ctz(mm);
                mm &= mm - 1;
                int n = q * 128 + ww * 32 + bit;
                int pos = atomicAdd(&s_cnt[b], 1);
                if (pos < CN_CAP) {
                    s_cnl[b][pos] = n;
                } else {
                    // overflow (i==j pairs: cnt ~ degree ~ 64): accumulate
                    // directly into the swizzled CN slots via LDS atomics.
                    const float* xn = x + (size_t)n * IN_CH;
                    for (int d = 0; d < IN_CH; ++d) {
                        int u = 32 + (d >> 2);
                        float* base = (float*)&s_xs4[b * 64 + (u ^ (b & 7))];
                        atomicAdd(&base[d & 3], xn[d]);
                    }
                }
            }
        }
    }

    // xij: unit s of row b
    s_xs4[b * 64 + (s ^ (b & 7))] =
        make_float4(va.x * vb.x, va.y * vb.y, va.z * vb.z, va.w * vb.w);

    // cn_emb: start from the slot (zero + any overflow contributions), add list
    {
        int cnt = s_cnt[b];                  // same-wave LDS ops: ordered
        if (cnt > CN_CAP) cnt = CN_CAP;
        int u = (32 + s) ^ (b & 7);
        float4 d0 = s_xs4[b * 64 + u];
        for (int c = 0; c < cnt; ++c) {
            const float4* xn4 = (const float4*)(x + (size_t)s_cnl[b][c] * IN_CH);
            float4 v = xn4[s];
            d0 = make_float4(d0.x + v.x, d0.y + v.y, d0.z + v.z, d0.w + v.w);
        }
        s_xs4[b * 64 + u] = d0;
    }
    __syncthreads();

    // ---- phase 2: MFMA. wave w covers n-tiles {2w, 2w+1}, all 16 pairs.
    const int w    = tid >> 6;       // wave 0..7
    const int lane = tid & 63;
    const int t0 = w * 2, t1 = w * 2 + 1;
    const int mr = lane & 15;   // A row = pair
    const int kb = lane >> 4;   // k-block 0..3

    f32x4 acc0 = {0.f, 0.f, 0.f, 0.f};
    f32x4 acc1 = {0.f, 0.f, 0.f, 0.f};

    const short8* W1B8 = (const short8*)W1B;
#pragma unroll
    for (int ks = 0; ks < 8; ++ks) {
        // A-frag: lane holds k = ks*32 + kb*8 + e of row mr (float4 units f0, f0+1)
        int f0 = ks * 8 + kb * 2;
        float4 x0 = s_xs4[mr * 64 + (f0 ^ (mr & 7))];
        float4 x1 = s_xs4[mr * 64 + ((f0 + 1) ^ (mr & 7))];
        short8 af;
        af[0] = f2bf(x0.x); af[1] = f2bf(x0.y); af[2] = f2bf(x0.z); af[3] = f2bf(x0.w);
        af[4] = f2bf(x1.x); af[5] = f2bf(x1.y); af[6] = f2bf(x1.z); af[7] = f2bf(x1.w);
        int fb = (ks * 16 + t0) * 64 + lane;
        short8 bf0 = W1B8[fb];
        short8 bf1 = W1B8[fb + 64];
        acc0 = __builtin_amdgcn_mfma_f32_16x16x32_bf16(af, bf0, acc0, 0, 0, 0);
        acc1 = __builtin_amdgcn_mfma_f32_16x16x32_bf16(af, bf1, acc1, 0, 0, 0);
    }

    // ---- epilogue: relu + layer 2 (fp32), reduce over h
    // C layout: col = lane&15 (n within tile), row = (lane>>4)*4 + reg (pair)
    const int ncol = lane & 15;
    const float b10 = b1[t0 * 16 + ncol];
    const float b11 = b1[t1 * 16 + ncol];
    const float w20 = W2[t0 * 16 + ncol];
    const float w21 = W2[t1 * 16 + ncol];

    float sum[4];
#pragma unroll
    for (int r = 0; r < 4; ++r)
        sum[r] = w20 * fmaxf(acc0[r] + b10, 0.f) + w21 * fmaxf(acc1[r] + b11, 0.f);

#pragma unroll
    for (int r = 0; r < 4; ++r) {
        float v = sum[r];
        v += __shfl_xor(v, 1);
        v += __shfl_xor(v, 2);
        v += __shfl_xor(v, 4);
        v += __shfl_xor(v, 8);
        if ((lane & 15) == 0) s_part[kb * 4 + r][w] = v;
    }
    __syncthreads();

    if (tid < TILE_B) {
        float r = b2[0];
#pragma unroll
        for (int ww = 0; ww < 8; ++ww) r += s_part[tid][ww];
        out[p0 + tid] = r;
    }
}

// -------------------------------------------------------------------- launch
extern "C" void kernel_launch(void* const* d_in, const int* in_sizes, int n_in,
                              void* d_out, int out_size, void* d_ws, size_t ws_size,
                              hipStream_t stream) {
    const float* x   = (const float*)d_in[0];
    const int*   ei  = (const int*)d_in[1];
    const int*   tei = (const int*)d_in[2];
    const float* W1  = (const float*)d_in[3];
    const float* b1  = (const float*)d_in[4];
    const float* W2  = (const float*)d_in[5];
    const float* b2  = (const float*)d_in[6];
    float* out = (float*)d_out;

    unsigned char* ws = (unsigned char*)d_ws;
    const size_t adj_bytes = (size_t)N_NODES * WPR * sizeof(unsigned int);   // 12.8 MB
    unsigned int* adj = (unsigned int*)ws;
    short* W1B = (short*)(ws + adj_bytes);                                   // 128 KB bf16

    zero_pack_kernel<<<ZERO_BLOCKS + PACK_BLOCKS, 256, 0, stream>>>((uint4*)adj, W1, W1B);
    build_adj_kernel<<<ADJ_BLOCKS, 256, 0, stream>>>(ei, adj);
    fused_kernel<<<N_PAIRS / TILE_B, 512, 0, stream>>>(x, tei, adj, W1B, b1, W2, b2, out);
}